// Round 1
// baseline (1919.552 us; speedup 1.0000x reference)
//
#include <hip/hip_runtime.h>
#include <hip/hip_bf16.h>

typedef unsigned short u16;
typedef unsigned int u32;

// Problem constants
#define NN 2048
#define DM 256
#define ED 16
#define HH 8
#define QK 32
#define VV 32
#define OUTD 256

// ---------- helpers ----------
__device__ __forceinline__ u16 f2bf(float f) {
    u32 u = __float_as_uint(f);
    u32 r = u + 0x7fffu + ((u >> 16) & 1u);   // round-to-nearest-even
    return (u16)(r >> 16);
}
__device__ __forceinline__ u32 pack2bf(float a, float b) {
    return (u32)f2bf(a) | ((u32)f2bf(b) << 16);
}
__device__ __forceinline__ void ld8(const u16* p, float* f) {
    const uint4 v = *reinterpret_cast<const uint4*>(p);
    f[0] = __uint_as_float(v.x << 16); f[1] = __uint_as_float(v.x & 0xffff0000u);
    f[2] = __uint_as_float(v.y << 16); f[3] = __uint_as_float(v.y & 0xffff0000u);
    f[4] = __uint_as_float(v.z << 16); f[5] = __uint_as_float(v.z & 0xffff0000u);
    f[6] = __uint_as_float(v.w << 16); f[7] = __uint_as_float(v.w & 0xffff0000u);
}

// ---------- K1: projections ----------
// grid 512 = 8 h * 64 n-tiles(32 rows), 256 thr
// q_ws fp32 [h][n][32] (scaled 1/sqrt(32)); qe_ws fp32 [h][n][16] (scaled);
// nk_ws bf16 [h][n][32]; nv_ws bf16 [h][n][32]
__global__ __launch_bounds__(256) void k1_precompute(
    const float* __restrict__ node_g, const float* __restrict__ qt_g,
    const float* __restrict__ nkt_g, const float* __restrict__ nvt_g,
    const float* __restrict__ ek_g,
    float* __restrict__ q_ws, float* __restrict__ qe_ws,
    u16* __restrict__ nk_ws, u16* __restrict__ nv_ws) {
    __shared__ __align__(16) float node_s[32][256];
    __shared__ __align__(16) float qtmp_s[32][32];
    const int t = threadIdx.x;
    const int h = blockIdx.x >> 6;
    const int n0 = (blockIdx.x & 63) * 32;
#pragma unroll
    for (int c = 0; c < 8; ++c) {
        const int ci = t + c * 256;
        const int nl = ci >> 6, d4 = ci & 63;
        *(float4*)&node_s[nl][d4 * 4] =
            *(const float4*)&node_g[(size_t)(n0 + nl) * 256 + d4 * 4];
    }
    __syncthreads();
    const int q = t & 31, nb = t >> 5;
    const float scale = 0.17677669529663689f;  // 1/sqrt(32)

#define PROJ_LOOP(Wp, STORE0, STORE1, STORE2, STORE3)                          \
    {                                                                          \
        const float* W = Wp;                                                   \
        float a0 = 0.f, a1 = 0.f, a2 = 0.f, a3 = 0.f;                          \
        for (int d4 = 0; d4 < 64; ++d4) {                                      \
            const float w0 = W[(d4 * 4 + 0) * 32 + q];                         \
            const float w1 = W[(d4 * 4 + 1) * 32 + q];                         \
            const float w2 = W[(d4 * 4 + 2) * 32 + q];                         \
            const float w3 = W[(d4 * 4 + 3) * 32 + q];                         \
            float4 nd;                                                         \
            nd = *(const float4*)&node_s[nb][d4 * 4];                          \
            a0 += nd.x * w0 + nd.y * w1 + nd.z * w2 + nd.w * w3;               \
            nd = *(const float4*)&node_s[nb + 8][d4 * 4];                      \
            a1 += nd.x * w0 + nd.y * w1 + nd.z * w2 + nd.w * w3;               \
            nd = *(const float4*)&node_s[nb + 16][d4 * 4];                     \
            a2 += nd.x * w0 + nd.y * w1 + nd.z * w2 + nd.w * w3;               \
            nd = *(const float4*)&node_s[nb + 24][d4 * 4];                     \
            a3 += nd.x * w0 + nd.y * w1 + nd.z * w2 + nd.w * w3;               \
        }                                                                      \
        STORE0; STORE1; STORE2; STORE3;                                        \
    }

    // query (scaled) -> q_ws + qtmp_s
    PROJ_LOOP(qt_g + h * (DM * QK),
        { float v = a0 * scale; q_ws[((size_t)h * NN + n0 + nb) * 32 + q] = v; qtmp_s[nb][q] = v; },
        { float v = a1 * scale; q_ws[((size_t)h * NN + n0 + nb + 8) * 32 + q] = v; qtmp_s[nb + 8][q] = v; },
        { float v = a2 * scale; q_ws[((size_t)h * NN + n0 + nb + 16) * 32 + q] = v; qtmp_s[nb + 16][q] = v; },
        { float v = a3 * scale; q_ws[((size_t)h * NN + n0 + nb + 24) * 32 + q] = v; qtmp_s[nb + 24][q] = v; })
    // node_key -> bf16
    PROJ_LOOP(nkt_g + h * (DM * QK),
        { nk_ws[((size_t)h * NN + n0 + nb) * 32 + q] = f2bf(a0); },
        { nk_ws[((size_t)h * NN + n0 + nb + 8) * 32 + q] = f2bf(a1); },
        { nk_ws[((size_t)h * NN + n0 + nb + 16) * 32 + q] = f2bf(a2); },
        { nk_ws[((size_t)h * NN + n0 + nb + 24) * 32 + q] = f2bf(a3); })
    // node_value -> bf16
    PROJ_LOOP(nvt_g + h * (DM * QK),
        { nv_ws[((size_t)h * NN + n0 + nb) * 32 + q] = f2bf(a0); },
        { nv_ws[((size_t)h * NN + n0 + nb + 8) * 32 + q] = f2bf(a1); },
        { nv_ws[((size_t)h * NN + n0 + nb + 16) * 32 + q] = f2bf(a2); },
        { nv_ws[((size_t)h * NN + n0 + nb + 24) * 32 + q] = f2bf(a3); })
#undef PROJ_LOOP
    __syncthreads();
    // qe[h,n,e] = sum_q qtmp[n][q] * ek[e][q]   (qtmp already scaled)
#pragma unroll
    for (int c = 0; c < 2; ++c) {
        const int idx = t + c * 256;
        const int nl = idx >> 4, e = idx & 15;
        float s = 0.f;
#pragma unroll
        for (int qq = 0; qq < 32; ++qq) s = fmaf(qtmp_s[nl][qq], ek_g[e * 32 + qq], s);
        qe_ws[((size_t)h * NN + n0 + nl) * 16 + e] = s;
    }
}

// ---------- K2: fused attention ----------
// grid 512 = 256 n-tiles(8 rows) * 2 m-halves, 256 thr
// thread role: r = t>>2 -> (h = r>>3, n_l = r&7); sub = t&3 splits m
// LDS: nk_s/nv_s bf16 [8][32][40-pad], ee_s bf16 [8][32*24+8-pad]
__global__ __launch_bounds__(256, 2) void k2_attn(
    const float* __restrict__ ee_g, const float* __restrict__ q_g,
    const float* __restrict__ qe_g, const u16* __restrict__ nk_g,
    const u16* __restrict__ nv_g, float* __restrict__ accv_ws,
    float* __restrict__ acce_ws, float* __restrict__ ml_ws) {
    __shared__ __align__(16) u16 nk_s[8 * 32 * 40];
    __shared__ __align__(16) u16 nv_s[8 * 32 * 40];
    __shared__ __align__(16) u16 ee_s[8 * 776];

    const int t = threadIdx.x;
    const int sub = t & 3;
    const int r = t >> 2;
    const int h = r >> 3;
    const int nl = r & 7;
    const int nt = blockIdx.x >> 1;
    const int half = blockIdx.x & 1;
    const int n0 = nt * 8;
    const int gn = n0 + nl;
    const int mbase = half * 1024;

    float q_r[32], qe_r[16];
    {
        const float* qp = q_g + ((size_t)h * NN + gn) * 32;
#pragma unroll
        for (int c = 0; c < 8; ++c) {
            float4 v = *(const float4*)&qp[c * 4];
            q_r[c * 4 + 0] = v.x; q_r[c * 4 + 1] = v.y;
            q_r[c * 4 + 2] = v.z; q_r[c * 4 + 3] = v.w;
        }
        const float* qep = qe_g + ((size_t)h * NN + gn) * 16;
#pragma unroll
        for (int c = 0; c < 4; ++c) {
            float4 v = *(const float4*)&qep[c * 4];
            qe_r[c * 4 + 0] = v.x; qe_r[c * 4 + 1] = v.y;
            qe_r[c * 4 + 2] = v.z; qe_r[c * 4 + 3] = v.w;
        }
    }
    float accv[32], acce[16];
#pragma unroll
    for (int k = 0; k < 32; ++k) accv[k] = 0.f;
#pragma unroll
    for (int k = 0; k < 16; ++k) acce[k] = 0.f;
    float M = -INFINITY, Lsum = 0.f;

#pragma unroll 1
    for (int it = 0; it < 32; ++it) {
        const int m0 = mbase + it * 32;
        __syncthreads();
        // fill nk/nv tiles (bf16 copy)
#pragma unroll
        for (int c = 0; c < 4; ++c) {
            const int ci = t + c * 256;
            const int hh = ci >> 7, mq = ci & 127, mm = mq >> 2, q16 = mq & 3;
            const size_t goff = ((size_t)hh * NN + m0 + mm) * 32 + q16 * 8;
            const int soff = (hh * 32 + mm) * 40 + q16 * 8;
            *(uint4*)&nk_s[soff] = *(const uint4*)&nk_g[goff];
            *(uint4*)&nv_s[soff] = *(const uint4*)&nv_g[goff];
        }
        // fill ee tile (fp32 -> bf16)
#pragma unroll
        for (int c = 0; c < 4; ++c) {
            const int ci = t + c * 256;
            const int nn2 = ci >> 7, mj = ci & 127, mm = mj >> 2, e4 = mj & 3;
            const float4 f =
                *(const float4*)&ee_g[((size_t)(n0 + nn2) * NN + m0 + mm) * 16 + e4 * 4];
            uint2 p;
            p.x = pack2bf(f.x, f.y);
            p.y = pack2bf(f.z, f.w);
            *(uint2*)&ee_s[nn2 * 776 + mm * 24 + e4 * 4] = p;
        }
        __syncthreads();

        // Phase A: logits for this thread's 8 m's
        float l_r[8];
#pragma unroll
        for (int i = 0; i < 8; ++i) {
            const int m = sub + 4 * i;
            const u16* nkp = &nk_s[(h * 32 + m) * 40];
            float acc = 0.f;
#pragma unroll
            for (int c = 0; c < 4; ++c) {
                float b[8];
                ld8(nkp + c * 8, b);
#pragma unroll
                for (int j = 0; j < 8; ++j) acc = fmaf(b[j], q_r[c * 8 + j], acc);
            }
            const u16* eep = &ee_s[nl * 776 + m * 24];
            float e0[8], e1[8];
            ld8(eep, e0);
            ld8(eep + 8, e1);
#pragma unroll
            for (int j = 0; j < 8; ++j) acc = fmaf(e0[j], qe_r[j], acc);
#pragma unroll
            for (int j = 0; j < 8; ++j) acc = fmaf(e1[j], qe_r[8 + j], acc);
            l_r[i] = acc;
        }
        // Phase B: online softmax bookkeeping (4 sub-threads per row)
        float tm = l_r[0];
#pragma unroll
        for (int i = 1; i < 8; ++i) tm = fmaxf(tm, l_r[i]);
        tm = fmaxf(tm, __shfl_xor(tm, 1));
        tm = fmaxf(tm, __shfl_xor(tm, 2));
        const float newM = fmaxf(M, tm);
        const float a = __expf(M - newM);
        Lsum *= a;
#pragma unroll
        for (int k = 0; k < 32; ++k) accv[k] *= a;
#pragma unroll
        for (int k = 0; k < 16; ++k) acce[k] *= a;
        // Phase C: accumulate P*V and P*EE
#pragma unroll
        for (int i = 0; i < 8; ++i) {
            const int m = sub + 4 * i;
            const float p = __expf(l_r[i] - newM);
            Lsum += p;
            const u16* nvp = &nv_s[(h * 32 + m) * 40];
#pragma unroll
            for (int c = 0; c < 4; ++c) {
                float b[8];
                ld8(nvp + c * 8, b);
#pragma unroll
                for (int j = 0; j < 8; ++j)
                    accv[c * 8 + j] = fmaf(p, b[j], accv[c * 8 + j]);
            }
            const u16* eep = &ee_s[nl * 776 + m * 24];
            float e0[8], e1[8];
            ld8(eep, e0);
            ld8(eep + 8, e1);
#pragma unroll
            for (int j = 0; j < 8; ++j) acce[j] = fmaf(p, e0[j], acce[j]);
#pragma unroll
            for (int j = 0; j < 8; ++j) acce[8 + j] = fmaf(p, e1[j], acce[8 + j]);
        }
        M = newM;
    }
    // reduce the 4 m-sub partials of each row
#pragma unroll
    for (int k = 0; k < 32; ++k) {
        accv[k] += __shfl_xor(accv[k], 1);
        accv[k] += __shfl_xor(accv[k], 2);
    }
#pragma unroll
    for (int k = 0; k < 16; ++k) {
        acce[k] += __shfl_xor(acce[k], 1);
        acce[k] += __shfl_xor(acce[k], 2);
    }
    Lsum += __shfl_xor(Lsum, 1);
    Lsum += __shfl_xor(Lsum, 2);
    if (sub == 0) {
        float* avp = accv_ws + (((size_t)half * 8 + h) * NN + gn) * 32;
#pragma unroll
        for (int c = 0; c < 8; ++c)
            *(float4*)&avp[c * 4] = make_float4(accv[c * 4], accv[c * 4 + 1],
                                                accv[c * 4 + 2], accv[c * 4 + 3]);
        float* aep = acce_ws + (((size_t)half * 8 + h) * NN + gn) * 16;
#pragma unroll
        for (int c = 0; c < 4; ++c)
            *(float4*)&aep[c * 4] = make_float4(acce[c * 4], acce[c * 4 + 1],
                                                acce[c * 4 + 2], acce[c * 4 + 3]);
        float* mlp = ml_ws + (((size_t)half * 8 + h) * NN + gn) * 2;
        mlp[0] = M;
        mlp[1] = Lsum;
    }
}

// ---------- K3: combine halves + edge-value projection + output GEMM ----------
// grid 256 (8 n-rows each), 256 thr
__global__ __launch_bounds__(256) void k3_combine(
    const float* __restrict__ accv_ws, const float* __restrict__ acce_ws,
    const float* __restrict__ ml_ws, const float* __restrict__ ev_g,
    const float* __restrict__ ot_g, float* __restrict__ out_g) {
    __shared__ float w_s[64][2];
    __shared__ float ae_s[8 * 8 * 16];
    __shared__ __align__(16) float av_s[256 * 8];  // [k=h*32+v][n_l]
    const int t = threadIdx.x;
    const int n0 = blockIdx.x * 8;
    if (t < 64) {
        const int h = t >> 3, nl = t & 7, gn = n0 + nl;
        const float M1 = ml_ws[((size_t)h * NN + gn) * 2 + 0];
        const float L1 = ml_ws[((size_t)h * NN + gn) * 2 + 1];
        const float M2 = ml_ws[((size_t)(8 + h) * NN + gn) * 2 + 0];
        const float L2 = ml_ws[((size_t)(8 + h) * NN + gn) * 2 + 1];
        const float Mx = fmaxf(M1, M2);
        const float a1 = __expf(M1 - Mx), a2 = __expf(M2 - Mx);
        const float inv = 1.0f / (a1 * L1 + a2 * L2);
        w_s[t][0] = a1 * inv;
        w_s[t][1] = a2 * inv;
    }
    __syncthreads();
#pragma unroll
    for (int c = 0; c < 4; ++c) {
        const int idx = t + c * 256;  // 1024 = 8n*8h*16e
        const int nl = idx >> 7, h = (idx >> 4) & 7, e = idx & 15;
        const int gn = n0 + nl;
        const float w1 = w_s[h * 8 + nl][0], w2 = w_s[h * 8 + nl][1];
        const float v1 = acce_ws[((size_t)h * NN + gn) * 16 + e];
        const float v2 = acce_ws[((size_t)(8 + h) * NN + gn) * 16 + e];
        ae_s[(nl * 8 + h) * 16 + e] = w1 * v1 + w2 * v2;
    }
    __syncthreads();
#pragma unroll
    for (int c = 0; c < 8; ++c) {
        const int idx = t + c * 256;  // 2048 = 8n*8h*32v
        const int nl = idx >> 8, h = (idx >> 5) & 7, v = idx & 31;
        const int gn = n0 + nl;
        const float w1 = w_s[h * 8 + nl][0], w2 = w_s[h * 8 + nl][1];
        float x = w1 * accv_ws[((size_t)h * NN + gn) * 32 + v] +
                  w2 * accv_ws[((size_t)(8 + h) * NN + gn) * 32 + v];
        const float* aep = &ae_s[(nl * 8 + h) * 16];
#pragma unroll
        for (int e = 0; e < 16; ++e) x = fmaf(aep[e], ev_g[e * 32 + v], x);
        av_s[(h * 32 + v) * 8 + nl] = x;
    }
    __syncthreads();
    {
        const int o = t;
        float r0 = 0, r1 = 0, r2 = 0, r3 = 0, r4 = 0, r5 = 0, r6 = 0, r7 = 0;
#pragma unroll 4
        for (int k = 0; k < 256; ++k) {
            const float w = ot_g[k * 256 + o];
            const float* av = &av_s[k * 8];
            r0 = fmaf(av[0], w, r0); r1 = fmaf(av[1], w, r1);
            r2 = fmaf(av[2], w, r2); r3 = fmaf(av[3], w, r3);
            r4 = fmaf(av[4], w, r4); r5 = fmaf(av[5], w, r5);
            r6 = fmaf(av[6], w, r6); r7 = fmaf(av[7], w, r7);
        }
        out_g[(size_t)(n0 + 0) * 256 + o] = r0;
        out_g[(size_t)(n0 + 1) * 256 + o] = r1;
        out_g[(size_t)(n0 + 2) * 256 + o] = r2;
        out_g[(size_t)(n0 + 3) * 256 + o] = r3;
        out_g[(size_t)(n0 + 4) * 256 + o] = r4;
        out_g[(size_t)(n0 + 5) * 256 + o] = r5;
        out_g[(size_t)(n0 + 6) * 256 + o] = r6;
        out_g[(size_t)(n0 + 7) * 256 + o] = r7;
    }
}

extern "C" void kernel_launch(void* const* d_in, const int* in_sizes, int n_in,
                              void* d_out, int out_size, void* d_ws, size_t ws_size,
                              hipStream_t stream) {
    (void)in_sizes; (void)n_in; (void)out_size; (void)ws_size;
    const float* ee = (const float*)d_in[0];
    const float* node = (const float*)d_in[1];
    const float* qt = (const float*)d_in[2];
    const float* nkt = (const float*)d_in[3];
    const float* ek = (const float*)d_in[4];
    const float* nvt = (const float*)d_in[5];
    const float* ev = (const float*)d_in[6];
    const float* ot = (const float*)d_in[7];
    float* out = (float*)d_out;

    char* ws = (char*)d_ws;
    // ws layout (bytes): needs ~11.3 MB total
    float* q_ws = (float*)(ws);                        // 2 MB  [8][2048][32] f32
    float* qe_ws = (float*)(ws + (2u << 20));          // 1 MB  [8][2048][16] f32
    u16* nk_ws = (u16*)(ws + (3u << 20));              // 1 MB  [8][2048][32] bf16
    u16* nv_ws = (u16*)(ws + (4u << 20));              // 1 MB  [8][2048][32] bf16
    float* accv_ws = (float*)(ws + (5u << 20));        // 4 MB  [2][8][2048][32] f32
    float* acce_ws = (float*)(ws + (9u << 20));        // 2 MB  [2][8][2048][16] f32
    float* ml_ws = (float*)(ws + (11u << 20));         // 256 KB [2][8][2048][2] f32

    hipLaunchKernelGGL(k1_precompute, dim3(512), dim3(256), 0, stream,
                       node, qt, nkt, nvt, ek, q_ws, qe_ws, nk_ws, nv_ws);
    hipLaunchKernelGGL(k2_attn, dim3(512), dim3(256), 0, stream,
                       ee, q_ws, qe_ws, nk_ws, nv_ws, accv_ws, acce_ws, ml_ws);
    hipLaunchKernelGGL(k3_combine, dim3(256), dim3(256), 0, stream,
                       accv_ws, acce_ws, ml_ws, ev, ot, out);
}

// Round 2
// 174.428 us; speedup vs baseline: 11.0048x; 11.0048x over previous
//
#include <hip/hip_runtime.h>
#include <hip/hip_bf16.h>

typedef unsigned short u16;
typedef unsigned int u32;
typedef __attribute__((ext_vector_type(8))) short bf16x8;
typedef __attribute__((ext_vector_type(4))) float f32x4;

#define NN 2048
#define DM 256
#define ED 16
#define HH 8
#define QK 32
#define VV 32
#define OUTD 256

// ---------- helpers ----------
__device__ __forceinline__ u16 f2bf(float f) {
    u32 u = __float_as_uint(f);
    u32 r = u + 0x7fffu + ((u >> 16) & 1u);   // round-to-nearest-even
    return (u16)(r >> 16);
}
__device__ __forceinline__ u32 pack2bf(float a, float b) {
    return (u32)f2bf(a) | ((u32)f2bf(b) << 16);
}

// ---------- K1: projections ----------
// grid 512 = 8 h * 64 n-tiles(32 rows), 256 thr
// qbf bf16 [h][n][32] (scaled 1/sqrt(32)); qebf bf16 [h][n][16] (scaled);
// nk bf16 [h][n][32]; nvT bf16 [h][v=32][n=2048] (transposed!)
__global__ __launch_bounds__(256) void k1_precompute(
    const float* __restrict__ node_g, const float* __restrict__ qt_g,
    const float* __restrict__ nkt_g, const float* __restrict__ nvt_g,
    const float* __restrict__ ek_g,
    u16* __restrict__ qbf, u16* __restrict__ qebf,
    u16* __restrict__ nk_ws, u16* __restrict__ nvT_ws) {
    __shared__ __align__(16) float node_s[32][256];
    __shared__ __align__(16) float qtmp_s[32][32];
    const int t = threadIdx.x;
    const int h = blockIdx.x >> 6;
    const int n0 = (blockIdx.x & 63) * 32;
#pragma unroll
    for (int c = 0; c < 8; ++c) {
        const int ci = t + c * 256;
        const int nl = ci >> 6, d4 = ci & 63;
        *(float4*)&node_s[nl][d4 * 4] =
            *(const float4*)&node_g[(size_t)(n0 + nl) * 256 + d4 * 4];
    }
    __syncthreads();
    const int q = t & 31, nb = t >> 5;
    const float scale = 0.17677669529663689f;  // 1/sqrt(32)

#define PROJ_LOOP(Wp, STORE0, STORE1, STORE2, STORE3)                          \
    {                                                                          \
        const float* W = Wp;                                                   \
        float a0 = 0.f, a1 = 0.f, a2 = 0.f, a3 = 0.f;                          \
        for (int d4 = 0; d4 < 64; ++d4) {                                      \
            const float w0 = W[(d4 * 4 + 0) * 32 + q];                         \
            const float w1 = W[(d4 * 4 + 1) * 32 + q];                         \
            const float w2 = W[(d4 * 4 + 2) * 32 + q];                         \
            const float w3 = W[(d4 * 4 + 3) * 32 + q];                         \
            float4 nd;                                                         \
            nd = *(const float4*)&node_s[nb][d4 * 4];                          \
            a0 += nd.x * w0 + nd.y * w1 + nd.z * w2 + nd.w * w3;               \
            nd = *(const float4*)&node_s[nb + 8][d4 * 4];                      \
            a1 += nd.x * w0 + nd.y * w1 + nd.z * w2 + nd.w * w3;               \
            nd = *(const float4*)&node_s[nb + 16][d4 * 4];                     \
            a2 += nd.x * w0 + nd.y * w1 + nd.z * w2 + nd.w * w3;               \
            nd = *(const float4*)&node_s[nb + 24][d4 * 4];                     \
            a3 += nd.x * w0 + nd.y * w1 + nd.z * w2 + nd.w * w3;               \
        }                                                                      \
        STORE0; STORE1; STORE2; STORE3;                                        \
    }

    // query (scaled) -> qtmp_s (f32) + qbf (bf16)
    PROJ_LOOP(qt_g + h * (DM * QK),
        { float v = a0 * scale; qtmp_s[nb][q] = v;      qbf[((size_t)h * NN + n0 + nb) * 32 + q] = f2bf(v); },
        { float v = a1 * scale; qtmp_s[nb + 8][q] = v;  qbf[((size_t)h * NN + n0 + nb + 8) * 32 + q] = f2bf(v); },
        { float v = a2 * scale; qtmp_s[nb + 16][q] = v; qbf[((size_t)h * NN + n0 + nb + 16) * 32 + q] = f2bf(v); },
        { float v = a3 * scale; qtmp_s[nb + 24][q] = v; qbf[((size_t)h * NN + n0 + nb + 24) * 32 + q] = f2bf(v); })
    // node_key -> bf16 [h][m][q]
    PROJ_LOOP(nkt_g + h * (DM * QK),
        { nk_ws[((size_t)h * NN + n0 + nb) * 32 + q] = f2bf(a0); },
        { nk_ws[((size_t)h * NN + n0 + nb + 8) * 32 + q] = f2bf(a1); },
        { nk_ws[((size_t)h * NN + n0 + nb + 16) * 32 + q] = f2bf(a2); },
        { nk_ws[((size_t)h * NN + n0 + nb + 24) * 32 + q] = f2bf(a3); })
    // node_value -> bf16 transposed [h][v][n]
    PROJ_LOOP(nvt_g + h * (DM * QK),
        { nvT_ws[((size_t)h * 32 + q) * NN + n0 + nb] = f2bf(a0); },
        { nvT_ws[((size_t)h * 32 + q) * NN + n0 + nb + 8] = f2bf(a1); },
        { nvT_ws[((size_t)h * 32 + q) * NN + n0 + nb + 16] = f2bf(a2); },
        { nvT_ws[((size_t)h * 32 + q) * NN + n0 + nb + 24] = f2bf(a3); })
#undef PROJ_LOOP
    __syncthreads();
    // qe[h,n,e] = sum_q qtmp[n][q] * ek[e][q]   (scaled) -> bf16
#pragma unroll
    for (int c = 0; c < 2; ++c) {
        const int idx = t + c * 256;
        const int nl = idx >> 4, e = idx & 15;
        float s = 0.f;
#pragma unroll
        for (int qq = 0; qq < 32; ++qq) s = fmaf(qtmp_s[nl][qq], ek_g[e * 32 + qq], s);
        qebf[((size_t)h * NN + n0 + nl) * 16 + e] = f2bf(s);
    }
}

// ---------- K2: fused MFMA attention ----------
// grid 512 = 128 n-tiles(16 rows) * 4 m-chunks(512 m each), 512 thr = 8 waves = 8 heads
// Per 32-m step: node logits via mfma(K,Q^T) [S^T layout], edge logits via
// per-n mfma(qe_n, ee_n^T) with heads as rows, online softmax over rows,
// PV via mfma(V^T, P^T), acce via per-n mfma(P_n, ee_n).
__global__ __launch_bounds__(512, 2) void k2_attn(
    const float* __restrict__ ee_g, const u16* __restrict__ qbf,
    const u16* __restrict__ qebf, const u16* __restrict__ nk_g,
    const u16* __restrict__ nvT_g, float* __restrict__ accv_ws,
    float* __restrict__ acce_ws, float* __restrict__ ml_ws) {
    // LDS: ee double-buffered bf16 [16n][32m][16e] (n-stride 520 u16 = 1040 B)
    __shared__ u16 ee_s[2][16 * 520];
    // P buffer bf16 [16n][16h][32m] (n-stride 520 u16; h 8..15 stay zero)
    __shared__ u16 p_s[16 * 520];
    // edge logits f32 [16n][8h][32m] (n-stride 260 f32 = 1040 B)
    __shared__ float el_s[16 * 260];
    // rescale factors f32 [16n][8h]
    __shared__ float a_s[16 * 8];

    const int t = threadIdx.x;
    const int w = t >> 6;          // wave = head
    const int l = t & 63;          // lane in wave
    const int col = l & 15;
    const int g = l >> 4;          // 0..3
    const int h = w;
    const int nt = blockIdx.x >> 2;
    const int ck = blockIdx.x & 3;
    const int n0 = nt * 16;
    const int mbase = ck * 512;
    const int sn = t >> 5, sm = t & 31;   // staging role: n-row, m

    // zero p_s rows h=8..15 (8 KB)
    {
        const int zn = t >> 5, zr = t & 31;
        const int zh = zr >> 2, zq = zr & 3;
        *(uint4*)&p_s[zn * 520 + (8 + zh) * 32 + zq * 8] = make_uint4(0, 0, 0, 0);
    }

    // persistent fragments
    const bf16x8 Qfrag = *(const bf16x8*)&qbf[((size_t)h * NN + n0 + col) * 32 + 8 * g];
    bf16x8 qeA[2];
#pragma unroll
    for (int s2 = 0; s2 < 2; ++s2) {
        bf16x8 z = {0, 0, 0, 0, 0, 0, 0, 0};
        if (col < 8 && g < 2)
            z = *(const bf16x8*)&qebf[((size_t)col * NN + n0 + 2 * w + s2) * 16 + 8 * g];
        qeA[s2] = z;
    }

    f32x4 accpv0 = {0.f, 0.f, 0.f, 0.f}, accpv1 = {0.f, 0.f, 0.f, 0.f};
    f32x4 acce0 = {0.f, 0.f, 0.f, 0.f}, acce1 = {0.f, 0.f, 0.f, 0.f};
    float M = -INFINITY, Ls = 0.f;

    // stage chunk 0
    float4 r0, r1, r2, r3;
    {
        const float* src = ee_g + ((size_t)(n0 + sn) * NN + mbase + sm) * 16;
        r0 = *(const float4*)(src);
        r1 = *(const float4*)(src + 4);
        r2 = *(const float4*)(src + 8);
        r3 = *(const float4*)(src + 12);
        u32 w0 = pack2bf(r0.x, r0.y), w1 = pack2bf(r0.z, r0.w);
        u32 w2 = pack2bf(r1.x, r1.y), w3 = pack2bf(r1.z, r1.w);
        u32 w4 = pack2bf(r2.x, r2.y), w5 = pack2bf(r2.z, r2.w);
        u32 w6 = pack2bf(r3.x, r3.y), w7 = pack2bf(r3.z, r3.w);
        *(uint4*)&ee_s[0][sn * 520 + sm * 16] = make_uint4(w0, w1, w2, w3);
        *(uint4*)&ee_s[0][sn * 520 + sm * 16 + 8] = make_uint4(w4, w5, w6, w7);
    }
    __syncthreads();

    const f32x4 zf = {0.f, 0.f, 0.f, 0.f};

#pragma unroll 1
    for (int it = 0; it < 16; ++it) {
        const int m0 = mbase + it * 32;
        const u16* eeb = ee_s[it & 1];

        // prefetch next chunk into regs (hides HBM under compute)
        if (it < 15) {
            const float* src = ee_g + ((size_t)(n0 + sn) * NN + m0 + 32 + sm) * 16;
            r0 = *(const float4*)(src);
            r1 = *(const float4*)(src + 4);
            r2 = *(const float4*)(src + 8);
            r3 = *(const float4*)(src + 12);
        }

        // step a: node logits S^T = K · Q^T  (two 16-m subtiles)
        f32x4 sn0, sn1;
        {
            const bf16x8 Kf0 = *(const bf16x8*)&nk_g[((size_t)h * NN + m0 + col) * 32 + 8 * g];
            const bf16x8 Kf1 = *(const bf16x8*)&nk_g[((size_t)h * NN + m0 + 16 + col) * 32 + 8 * g];
            sn0 = __builtin_amdgcn_mfma_f32_16x16x32_bf16(Kf0, Qfrag, zf, 0, 0, 0);
            sn1 = __builtin_amdgcn_mfma_f32_16x16x32_bf16(Kf1, Qfrag, zf, 0, 0, 0);
        }

        // step b: edge logits per n-slot: D[h][m] = qe_n · ee_n^T
#pragma unroll
        for (int s2 = 0; s2 < 2; ++s2) {
            const int nsl = 2 * w + s2;
#pragma unroll
            for (int s = 0; s < 2; ++s) {
                bf16x8 Bf = {0, 0, 0, 0, 0, 0, 0, 0};
                if (g < 2)
                    Bf = *(const bf16x8*)&eeb[nsl * 520 + (s * 16 + col) * 16 + 8 * g];
                f32x4 d = __builtin_amdgcn_mfma_f32_16x16x32_bf16(qeA[s2], Bf, zf, 0, 0, 0);
                if (l < 32) {  // rows h = 4g+reg < 8
#pragma unroll
                    for (int reg = 0; reg < 4; ++reg)
                        el_s[nsl * 260 + (4 * g + reg) * 32 + s * 16 + col] = d[reg];
                }
            }
        }
        __syncthreads();

        // step d: combine logits + online softmax (row = m, col = n)
        {
            const float4 e0 = *(const float4*)&el_s[col * 260 + h * 32 + 4 * g];
            const float4 e1 = *(const float4*)&el_s[col * 260 + h * 32 + 16 + 4 * g];
            float lv[8];
            lv[0] = sn0[0] + e0.x; lv[1] = sn0[1] + e0.y;
            lv[2] = sn0[2] + e0.z; lv[3] = sn0[3] + e0.w;
            lv[4] = sn1[0] + e1.x; lv[5] = sn1[1] + e1.y;
            lv[6] = sn1[2] + e1.z; lv[7] = sn1[3] + e1.w;
            float tm = fmaxf(fmaxf(fmaxf(lv[0], lv[1]), fmaxf(lv[2], lv[3])),
                             fmaxf(fmaxf(lv[4], lv[5]), fmaxf(lv[6], lv[7])));
            tm = fmaxf(tm, __shfl_xor(tm, 16));
            tm = fmaxf(tm, __shfl_xor(tm, 32));
            const float nM = fmaxf(M, tm);
            const float a = __expf(M - nM);
            M = nM;
            Ls *= a;
#pragma unroll
            for (int r = 0; r < 4; ++r) { accpv0[r] *= a; accpv1[r] *= a; }
            float p[8];
#pragma unroll
            for (int i = 0; i < 8; ++i) { p[i] = __expf(lv[i] - nM); Ls += p[i]; }
            // write P (bf16) [n=col][h][m]
            uint2 pk0, pk1;
            pk0.x = pack2bf(p[0], p[1]); pk0.y = pack2bf(p[2], p[3]);
            pk1.x = pack2bf(p[4], p[5]); pk1.y = pack2bf(p[6], p[7]);
            *(uint2*)&p_s[col * 520 + h * 32 + 4 * g] = pk0;
            *(uint2*)&p_s[col * 520 + h * 32 + 16 + 4 * g] = pk1;
            if (l < 16) a_s[col * 8 + h] = a;
        }
        __syncthreads();

        // step g: PV: D[v][n] += V^T · P^T   (own head)
        {
            const bf16x8 Pf = *(const bf16x8*)&p_s[col * 520 + h * 32 + 8 * g];
            const bf16x8 Vf0 = *(const bf16x8*)&nvT_g[((size_t)h * 32 + col) * NN + m0 + 8 * g];
            const bf16x8 Vf1 = *(const bf16x8*)&nvT_g[((size_t)h * 32 + 16 + col) * NN + m0 + 8 * g];
            accpv0 = __builtin_amdgcn_mfma_f32_16x16x32_bf16(Vf0, Pf, accpv0, 0, 0, 0);
            accpv1 = __builtin_amdgcn_mfma_f32_16x16x32_bf16(Vf1, Pf, accpv1, 0, 0, 0);
        }

        // step h: acce per n-slot: D[h][e] = a∘D + P_n · ee_n
#pragma unroll
        for (int s2 = 0; s2 < 2; ++s2) {
            const int nsl = 2 * w + s2;
            const float4 av = *(const float4*)&a_s[nsl * 8 + ((4 * g) & 7)];
            f32x4 acc = (s2 == 0) ? acce0 : acce1;
            acc[0] *= av.x; acc[1] *= av.y; acc[2] *= av.z; acc[3] *= av.w;
            const bf16x8 Pn = *(const bf16x8*)&p_s[nsl * 520 + col * 32 + 8 * g];
            bf16x8 Ef;
#pragma unroll
            for (int j = 0; j < 8; ++j)
                Ef[j] = (short)eeb[nsl * 520 + (8 * g + j) * 16 + col];
            acc = __builtin_amdgcn_mfma_f32_16x16x32_bf16(Pn, Ef, acc, 0, 0, 0);
            if (s2 == 0) acce0 = acc; else acce1 = acc;
        }

        // staging write of next chunk into other buffer
        if (it < 15) {
            u32 w0 = pack2bf(r0.x, r0.y), w1 = pack2bf(r0.z, r0.w);
            u32 w2 = pack2bf(r1.x, r1.y), w3 = pack2bf(r1.z, r1.w);
            u32 w4 = pack2bf(r2.x, r2.y), w5 = pack2bf(r2.z, r2.w);
            u32 w6 = pack2bf(r3.x, r3.y), w7 = pack2bf(r3.z, r3.w);
            u16* dst = (u16*)ee_s[(it + 1) & 1];
            *(uint4*)&dst[sn * 520 + sm * 16] = make_uint4(w0, w1, w2, w3);
            *(uint4*)&dst[sn * 520 + sm * 16 + 8] = make_uint4(w4, w5, w6, w7);
        }
        __syncthreads();
    }

    // epilogue: reduce Ls across g-groups (m partials)
    Ls += __shfl_xor(Ls, 16);
    Ls += __shfl_xor(Ls, 32);

    // accv: D[v][n]: col=n, row=v-local
    {
        float* avp = accv_ws + (((size_t)ck * 8 + h) * NN + n0 + col) * 32;
#pragma unroll
        for (int reg = 0; reg < 4; ++reg) {
            avp[4 * g + reg] = accpv0[reg];
            avp[16 + 4 * g + reg] = accpv1[reg];
        }
    }
    // acce: D[h][e] per n-slot: col=e, row=h (valid rows 0..7 -> l<32)
    if (l < 32) {
#pragma unroll
        for (int s2 = 0; s2 < 2; ++s2) {
            const f32x4 acc = (s2 == 0) ? acce0 : acce1;
#pragma unroll
            for (int reg = 0; reg < 4; ++reg) {
                const int hr = 4 * g + reg;
                acce_ws[(((size_t)ck * 8 + hr) * NN + n0 + 2 * w + s2) * 16 + col] = acc[reg];
            }
        }
    }
    if (l < 16) {
        float* mlp = ml_ws + (((size_t)ck * 8 + h) * NN + n0 + col) * 2;
        mlp[0] = M;
        mlp[1] = Ls;
    }
}

// ---------- K3: combine 4 m-chunks + edge-value projection + output GEMM ----------
// grid 256 (8 n-rows each), 256 thr
__global__ __launch_bounds__(256) void k3_combine(
    const float* __restrict__ accv_ws, const float* __restrict__ acce_ws,
    const float* __restrict__ ml_ws, const float* __restrict__ ev_g,
    const float* __restrict__ ot_g, float* __restrict__ out_g) {
    __shared__ float w_s[64][4];
    __shared__ float ae_s[8 * 8 * 16];
    __shared__ __align__(16) float av_s[256 * 8];  // [k=h*32+v][n_l]
    const int t = threadIdx.x;
    const int n0 = blockIdx.x * 8;
    if (t < 64) {
        const int h = t >> 3, nl = t & 7, gn = n0 + nl;
        float Mc[4], Lc[4];
#pragma unroll
        for (int c = 0; c < 4; ++c) {
            Mc[c] = ml_ws[(((size_t)c * 8 + h) * NN + gn) * 2 + 0];
            Lc[c] = ml_ws[(((size_t)c * 8 + h) * NN + gn) * 2 + 1];
        }
        float Mx = fmaxf(fmaxf(Mc[0], Mc[1]), fmaxf(Mc[2], Mc[3]));
        float ex[4], den = 0.f;
#pragma unroll
        for (int c = 0; c < 4; ++c) { ex[c] = __expf(Mc[c] - Mx); den += ex[c] * Lc[c]; }
        const float inv = 1.0f / den;
#pragma unroll
        for (int c = 0; c < 4; ++c) w_s[t][c] = ex[c] * inv;
    }
    __syncthreads();
#pragma unroll
    for (int c2 = 0; c2 < 4; ++c2) {
        const int idx = t + c2 * 256;  // 1024 = 8n*8h*16e
        const int nl = idx >> 7, h = (idx >> 4) & 7, e = idx & 15;
        const int gn = n0 + nl;
        float s = 0.f;
#pragma unroll
        for (int c = 0; c < 4; ++c)
            s += w_s[h * 8 + nl][c] * acce_ws[(((size_t)c * 8 + h) * NN + gn) * 16 + e];
        ae_s[(nl * 8 + h) * 16 + e] = s;
    }
    __syncthreads();
#pragma unroll
    for (int c2 = 0; c2 < 8; ++c2) {
        const int idx = t + c2 * 256;  // 2048 = 8n*8h*32v
        const int nl = idx >> 8, h = (idx >> 5) & 7, v = idx & 31;
        const int gn = n0 + nl;
        float x = 0.f;
#pragma unroll
        for (int c = 0; c < 4; ++c)
            x += w_s[h * 8 + nl][c] * accv_ws[(((size_t)c * 8 + h) * NN + gn) * 32 + v];
        const float* aep = &ae_s[(nl * 8 + h) * 16];
#pragma unroll
        for (int e = 0; e < 16; ++e) x = fmaf(aep[e], ev_g[e * 32 + v], x);
        av_s[(h * 32 + v) * 8 + nl] = x;
    }
    __syncthreads();
    {
        const int o = t;
        float r0 = 0, r1 = 0, r2 = 0, r3 = 0, r4 = 0, r5 = 0, r6 = 0, r7 = 0;
#pragma unroll 4
        for (int k = 0; k < 256; ++k) {
            const float w = ot_g[k * 256 + o];
            const float* av = &av_s[k * 8];
            r0 = fmaf(av[0], w, r0); r1 = fmaf(av[1], w, r1);
            r2 = fmaf(av[2], w, r2); r3 = fmaf(av[3], w, r3);
            r4 = fmaf(av[4], w, r4); r5 = fmaf(av[5], w, r5);
            r6 = fmaf(av[6], w, r6); r7 = fmaf(av[7], w, r7);
        }
        out_g[(size_t)(n0 + 0) * 256 + o] = r0;
        out_g[(size_t)(n0 + 1) * 256 + o] = r1;
        out_g[(size_t)(n0 + 2) * 256 + o] = r2;
        out_g[(size_t)(n0 + 3) * 256 + o] = r3;
        out_g[(size_t)(n0 + 4) * 256 + o] = r4;
        out_g[(size_t)(n0 + 5) * 256 + o] = r5;
        out_g[(size_t)(n0 + 6) * 256 + o] = r6;
        out_g[(size_t)(n0 + 7) * 256 + o] = r7;
    }
}

extern "C" void kernel_launch(void* const* d_in, const int* in_sizes, int n_in,
                              void* d_out, int out_size, void* d_ws, size_t ws_size,
                              hipStream_t stream) {
    (void)in_sizes; (void)n_in; (void)out_size; (void)ws_size;
    const float* ee = (const float*)d_in[0];
    const float* node = (const float*)d_in[1];
    const float* qt = (const float*)d_in[2];
    const float* nkt = (const float*)d_in[3];
    const float* ek = (const float*)d_in[4];
    const float* nvt = (const float*)d_in[5];
    const float* ev = (const float*)d_in[6];
    const float* ot = (const float*)d_in[7];
    float* out = (float*)d_out;

    char* ws = (char*)d_ws;
    // ws layout (bytes), ~16 MB total
    u16* qbf = (u16*)(ws);                            // 1 MB  [8][2048][32] bf16
    u16* qebf = (u16*)(ws + (1u << 20));              // 0.5 MB [8][2048][16] bf16
    u16* nk_ws = (u16*)(ws + (1u << 20) + (1u << 19));// 1 MB  [8][2048][32] bf16
    u16* nvT_ws = (u16*)(ws + (2u << 20) + (1u << 19));// 1 MB [8][32][2048] bf16
    float* accv_ws = (float*)(ws + (3u << 20) + (1u << 19)); // 8 MB [4][8][2048][32]
    float* acce_ws = (float*)(ws + (11u << 20) + (1u << 19));// 4 MB [4][8][2048][16]
    float* ml_ws = (float*)(ws + (15u << 20) + (1u << 19));  // 0.5 MB [4][8][2048][2]

    hipLaunchKernelGGL(k1_precompute, dim3(512), dim3(256), 0, stream,
                       node, qt, nkt, nvt, ek, qbf, qebf, nk_ws, nvT_ws);
    hipLaunchKernelGGL(k2_attn, dim3(512), dim3(512), 0, stream,
                       ee, qbf, qebf, nk_ws, nvT_ws, accv_ws, acce_ws, ml_ws);
    hipLaunchKernelGGL(k3_combine, dim3(256), dim3(256), 0, stream,
                       accv_ws, acce_ws, ml_ws, ev, ot, out);
}

// Round 5
// 152.022 us; speedup vs baseline: 12.6268x; 1.1474x over previous
//
#include <hip/hip_runtime.h>
#include <hip/hip_bf16.h>

typedef unsigned short u16;
typedef unsigned int u32;
typedef __attribute__((ext_vector_type(8))) short bf16x8;
typedef __attribute__((ext_vector_type(4))) float f32x4;

#define NN 2048
#define DM 256
#define ED 16
#define HH 8
#define QK 32
#define VV 32
#define OUTD 256

// ---------- helpers ----------
__device__ __forceinline__ u16 f2bf(float f) {
    __hip_bfloat16 h = __float2bfloat16(f);
    return *reinterpret_cast<u16*>(&h);
}
__device__ __forceinline__ u32 cvt2(float a, float b) {
    __hip_bfloat162 h = __float22bfloat162_rn(make_float2(a, b));
    return *reinterpret_cast<u32*>(&h);
}

// ---------- K1: projections ----------
// grid 512 = 8 h * 64 n-tiles(32 rows), 256 thr
// qbf bf16 [h][n][32] (scaled 1/sqrt(32)); qebf bf16 [h][n][16] (scaled);
// nk bf16 [h][m][32]; nvT bf16 [h][v=32][n=2048] (plain transpose)
__global__ __launch_bounds__(256) void k1_precompute(
    const float* __restrict__ node_g, const float* __restrict__ qt_g,
    const float* __restrict__ nkt_g, const float* __restrict__ nvt_g,
    const float* __restrict__ ek_g,
    u16* __restrict__ qbf, u16* __restrict__ qebf,
    u16* __restrict__ nk_ws, u16* __restrict__ nvT_ws) {
    __shared__ __align__(16) float node_s[32][256];
    __shared__ __align__(16) float qtmp_s[32][32];
    const int t = threadIdx.x;
    const int h = blockIdx.x >> 6;
    const int n0 = (blockIdx.x & 63) * 32;
#pragma unroll
    for (int c = 0; c < 8; ++c) {
        const int ci = t + c * 256;
        const int nl = ci >> 6, d4 = ci & 63;
        *(float4*)&node_s[nl][d4 * 4] =
            *(const float4*)&node_g[(size_t)(n0 + nl) * 256 + d4 * 4];
    }
    __syncthreads();
    const int q = t & 31, nb = t >> 5;
    const float scale = 0.17677669529663689f;  // 1/sqrt(32)

#define PROJ_LOOP(Wp, STORE0, STORE1, STORE2, STORE3)                          \
    {                                                                          \
        const float* W = Wp;                                                   \
        float a0 = 0.f, a1 = 0.f, a2 = 0.f, a3 = 0.f;                          \
        for (int d4 = 0; d4 < 64; ++d4) {                                      \
            const float w0 = W[(d4 * 4 + 0) * 32 + q];                         \
            const float w1 = W[(d4 * 4 + 1) * 32 + q];                         \
            const float w2 = W[(d4 * 4 + 2) * 32 + q];                         \
            const float w3 = W[(d4 * 4 + 3) * 32 + q];                         \
            float4 nd;                                                         \
            nd = *(const float4*)&node_s[nb][d4 * 4];                          \
            a0 += nd.x * w0 + nd.y * w1 + nd.z * w2 + nd.w * w3;               \
            nd = *(const float4*)&node_s[nb + 8][d4 * 4];                      \
            a1 += nd.x * w0 + nd.y * w1 + nd.z * w2 + nd.w * w3;               \
            nd = *(const float4*)&node_s[nb + 16][d4 * 4];                     \
            a2 += nd.x * w0 + nd.y * w1 + nd.z * w2 + nd.w * w3;               \
            nd = *(const float4*)&node_s[nb + 24][d4 * 4];                     \
            a3 += nd.x * w0 + nd.y * w1 + nd.z * w2 + nd.w * w3;               \
        }                                                                      \
        STORE0; STORE1; STORE2; STORE3;                                        \
    }

    // query (scaled) -> qtmp_s (f32) + qbf (bf16)
    PROJ_LOOP(qt_g + h * (DM * QK),
        { float v = a0 * scale; qtmp_s[nb][q] = v;      qbf[((size_t)h * NN + n0 + nb) * 32 + q] = f2bf(v); },
        { float v = a1 * scale; qtmp_s[nb + 8][q] = v;  qbf[((size_t)h * NN + n0 + nb + 8) * 32 + q] = f2bf(v); },
        { float v = a2 * scale; qtmp_s[nb + 16][q] = v; qbf[((size_t)h * NN + n0 + nb + 16) * 32 + q] = f2bf(v); },
        { float v = a3 * scale; qtmp_s[nb + 24][q] = v; qbf[((size_t)h * NN + n0 + nb + 24) * 32 + q] = f2bf(v); })
    // node_key -> bf16 [h][m][q]
    PROJ_LOOP(nkt_g + h * (DM * QK),
        { nk_ws[((size_t)h * NN + n0 + nb) * 32 + q] = f2bf(a0); },
        { nk_ws[((size_t)h * NN + n0 + nb + 8) * 32 + q] = f2bf(a1); },
        { nk_ws[((size_t)h * NN + n0 + nb + 16) * 32 + q] = f2bf(a2); },
        { nk_ws[((size_t)h * NN + n0 + nb + 24) * 32 + q] = f2bf(a3); })
    // node_value -> bf16 transposed [h][v][n]
    PROJ_LOOP(nvt_g + h * (DM * QK),
        { nvT_ws[((size_t)h * 32 + q) * NN + n0 + nb] = f2bf(a0); },
        { nvT_ws[((size_t)h * 32 + q) * NN + n0 + nb + 8] = f2bf(a1); },
        { nvT_ws[((size_t)h * 32 + q) * NN + n0 + nb + 16] = f2bf(a2); },
        { nvT_ws[((size_t)h * 32 + q) * NN + n0 + nb + 24] = f2bf(a3); })
#undef PROJ_LOOP
    __syncthreads();
    // qe[h,n,e] = sum_q qtmp[n][q] * ek[e][q]   (scaled) -> bf16
#pragma unroll
    for (int c = 0; c < 2; ++c) {
        const int idx = t + c * 256;
        const int nl = idx >> 4, e = idx & 15;
        float s = 0.f;
#pragma unroll
        for (int qq = 0; qq < 32; ++qq) s = fmaf(qtmp_s[nl][qq], ek_g[e * 32 + qq], s);
        qebf[((size_t)h * NN + n0 + nl) * 16 + e] = f2bf(s);
    }
}

// ---------- K2: fused MFMA attention ----------
// grid 512 = 128 n-tiles(16 rows) * 4 m-chunks(512 m each), 512 thr = 8 waves = 8 heads
__global__ __launch_bounds__(512, 2) void k2_attn(
    const float* __restrict__ ee_g, const u16* __restrict__ qbf,
    const u16* __restrict__ qebf, const u16* __restrict__ nk_g,
    const u16* __restrict__ nvT_g, float* __restrict__ accv_ws,
    float* __restrict__ acce_ws, float* __restrict__ ml_ws) {
    // ee (natural, e-contig) double-buffered bf16 [16n][32m][16e] (n-stride 520 u16)
    __shared__ __align__(16) u16 ee_s[2][16 * 520];
    // ee transposed (m-contig) single-buffered bf16 [16n][16e][32m+8pad] (e-stride 40, n-stride 640)
    // written at TOP of each iter (chunk it), read in step h (chunk it) — barrier-separated both ways
    __shared__ __align__(16) u16 eeT_s[16 * 640];
    // edge logits f32 [16n][8h][32m] (n-stride 260)
    __shared__ __align__(16) float el_s[16 * 260];
    // P bf16 [16n][8h][32m] plain order (n-stride 264); all elements rewritten each iter
    __shared__ __align__(16) u16 p_s[16 * 264];
    // rescale factors f32 [16n][8h]
    __shared__ float a_s[16 * 8];

    const int t = threadIdx.x;
    const int w = t >> 6;          // wave = head
    const int l = t & 63;
    const int col = l & 15;
    const int g = l >> 4;          // 0..3
    const int h = w;
    const int nt = blockIdx.x >> 2;
    const int ck = blockIdx.x & 3;
    const int n0 = nt * 16;
    const int mbase = ck * 512;
    const int sn = t >> 5, sm = t & 31;   // staging role: n-row, m

    // persistent fragments
    const bf16x8 Qfrag = *(const bf16x8*)&qbf[((size_t)h * NN + n0 + col) * 32 + 8 * g];
    bf16x8 qeA[2];
#pragma unroll
    for (int s2 = 0; s2 < 2; ++s2) {
        bf16x8 z = {0, 0, 0, 0, 0, 0, 0, 0};
        if (col < 8 && g < 2)
            z = *(const bf16x8*)&qebf[((size_t)col * NN + n0 + 2 * w + s2) * 16 + 8 * g];
        qeA[s2] = z;
    }

    f32x4 accpv0 = {0.f, 0.f, 0.f, 0.f}, accpv1 = {0.f, 0.f, 0.f, 0.f};
    f32x4 acce0 = {0.f, 0.f, 0.f, 0.f}, acce1 = {0.f, 0.f, 0.f, 0.f};
    float M = -INFINITY, Ls = 0.f;

    // stage chunk 0 into ee_s[0]; regs keep chunk 0 for the iter-0 eeT write
    float4 r0, r1, r2, r3;
    {
        const float* src = ee_g + ((size_t)(n0 + sn) * NN + mbase + sm) * 16;
        r0 = *(const float4*)(src);
        r1 = *(const float4*)(src + 4);
        r2 = *(const float4*)(src + 8);
        r3 = *(const float4*)(src + 12);
        *(uint4*)&ee_s[0][sn * 520 + sm * 16] =
            make_uint4(cvt2(r0.x, r0.y), cvt2(r0.z, r0.w), cvt2(r1.x, r1.y), cvt2(r1.z, r1.w));
        *(uint4*)&ee_s[0][sn * 520 + sm * 16 + 8] =
            make_uint4(cvt2(r2.x, r2.y), cvt2(r2.z, r2.w), cvt2(r3.x, r3.y), cvt2(r3.z, r3.w));
    }
    __syncthreads();

    const f32x4 zf = {0.f, 0.f, 0.f, 0.f};

#pragma unroll 1
    for (int it = 0; it < 16; ++it) {
        const int m0 = mbase + it * 32;
        const u16* eeb = ee_s[it & 1];

        // write eeT for CURRENT chunk from regs (before prefetch overwrites them).
        // Reads of chunk it-1 (step h, prev iter) are behind the loop-end barrier;
        // reads of chunk it (step h, this iter) are behind the step-b barrier.
        {
            u16* dst = &eeT_s[sn * 640 + sm];
            dst[0 * 40] = f2bf(r0.x);  dst[1 * 40] = f2bf(r0.y);
            dst[2 * 40] = f2bf(r0.z);  dst[3 * 40] = f2bf(r0.w);
            dst[4 * 40] = f2bf(r1.x);  dst[5 * 40] = f2bf(r1.y);
            dst[6 * 40] = f2bf(r1.z);  dst[7 * 40] = f2bf(r1.w);
            dst[8 * 40] = f2bf(r2.x);  dst[9 * 40] = f2bf(r2.y);
            dst[10 * 40] = f2bf(r2.z); dst[11 * 40] = f2bf(r2.w);
            dst[12 * 40] = f2bf(r3.x); dst[13 * 40] = f2bf(r3.y);
            dst[14 * 40] = f2bf(r3.z); dst[15 * 40] = f2bf(r3.w);
        }

        // prefetch next chunk into regs
        if (it < 15) {
            const float* src = ee_g + ((size_t)(n0 + sn) * NN + m0 + 32 + sm) * 16;
            r0 = *(const float4*)(src);
            r1 = *(const float4*)(src + 4);
            r2 = *(const float4*)(src + 8);
            r3 = *(const float4*)(src + 12);
        }

        // step a: node logits S^T = K · Q^T  (two 16-m subtiles)
        f32x4 sn0, sn1;
        {
            const bf16x8 Kf0 = *(const bf16x8*)&nk_g[((size_t)h * NN + m0 + col) * 32 + 8 * g];
            const bf16x8 Kf1 = *(const bf16x8*)&nk_g[((size_t)h * NN + m0 + 16 + col) * 32 + 8 * g];
            sn0 = __builtin_amdgcn_mfma_f32_16x16x32_bf16(Kf0, Qfrag, zf, 0, 0, 0);
            sn1 = __builtin_amdgcn_mfma_f32_16x16x32_bf16(Kf1, Qfrag, zf, 0, 0, 0);
        }

        // step b: edge logits per n-slot: D[h][m] = qe_n · ee_n^T
#pragma unroll
        for (int s2 = 0; s2 < 2; ++s2) {
            const int nsl = 2 * w + s2;
#pragma unroll
            for (int s = 0; s < 2; ++s) {
                bf16x8 Bf = {0, 0, 0, 0, 0, 0, 0, 0};
                if (g < 2)
                    Bf = *(const bf16x8*)&eeb[nsl * 520 + (s * 16 + col) * 16 + 8 * g];
                f32x4 d = __builtin_amdgcn_mfma_f32_16x16x32_bf16(qeA[s2], Bf, zf, 0, 0, 0);
                if (l < 32) {  // rows h = 4g+reg < 8
#pragma unroll
                    for (int reg = 0; reg < 4; ++reg)
                        el_s[nsl * 260 + (4 * g + reg) * 32 + s * 16 + col] = d[reg];
                }
            }
        }
        __syncthreads();

        // step d: combine logits + online softmax (thread owns n=col, m rows 4g+r / 16+4g+r)
        {
            const float4 e0 = *(const float4*)&el_s[col * 260 + h * 32 + 4 * g];
            const float4 e1 = *(const float4*)&el_s[col * 260 + h * 32 + 16 + 4 * g];
            float lv[8];
            lv[0] = sn0[0] + e0.x; lv[1] = sn0[1] + e0.y;
            lv[2] = sn0[2] + e0.z; lv[3] = sn0[3] + e0.w;
            lv[4] = sn1[0] + e1.x; lv[5] = sn1[1] + e1.y;
            lv[6] = sn1[2] + e1.z; lv[7] = sn1[3] + e1.w;
            float tm = fmaxf(fmaxf(fmaxf(lv[0], lv[1]), fmaxf(lv[2], lv[3])),
                             fmaxf(fmaxf(lv[4], lv[5]), fmaxf(lv[6], lv[7])));
            tm = fmaxf(tm, __shfl_xor(tm, 16));
            tm = fmaxf(tm, __shfl_xor(tm, 32));
            const float nM = fmaxf(M, tm);
            const float a = __expf(M - nM);
            M = nM;
            Ls *= a;
#pragma unroll
            for (int r = 0; r < 4; ++r) { accpv0[r] *= a; accpv1[r] *= a; }
            float p[8];
#pragma unroll
            for (int i = 0; i < 8; ++i) { p[i] = __expf(lv[i] - nM); Ls += p[i]; }
            // write P in plain m-order: m=4g+i and m=16+4g+i
            uint2 pk0, pk1;
            pk0.x = cvt2(p[0], p[1]); pk0.y = cvt2(p[2], p[3]);
            pk1.x = cvt2(p[4], p[5]); pk1.y = cvt2(p[6], p[7]);
            *(uint2*)&p_s[col * 264 + h * 32 + 4 * g] = pk0;
            *(uint2*)&p_s[col * 264 + h * 32 + 16 + 4 * g] = pk1;
            if (l < 16) a_s[col * 8 + h] = a;
        }
        __syncthreads();

        // step g: PV: D[v][n] += V^T · P^T   (own head; plain m-order both sides)
        {
            const bf16x8 Pf = *(const bf16x8*)&p_s[col * 264 + h * 32 + 8 * g];
            const bf16x8 Vf0 = *(const bf16x8*)&nvT_g[((size_t)h * 32 + col) * NN + m0 + 8 * g];
            const bf16x8 Vf1 = *(const bf16x8*)&nvT_g[((size_t)h * 32 + 16 + col) * NN + m0 + 8 * g];
            accpv0 = __builtin_amdgcn_mfma_f32_16x16x32_bf16(Vf0, Pf, accpv0, 0, 0, 0);
            accpv1 = __builtin_amdgcn_mfma_f32_16x16x32_bf16(Vf1, Pf, accpv1, 0, 0, 0);
        }

        // step h: acce per n-slot: D[h][e] = a∘D + P_n · ee_n
        // B from eeT (m-contig): B[k=8g+j][col=e] = eeT[nsl][col][8g+j] == ee[nsl][8g+j][col]
        {
            const bf16x8 Pn0 = *(const bf16x8*)&p_s[(2 * w + 0) * 264 + (col & 7) * 32 + 8 * g];
            const bf16x8 Pn1 = *(const bf16x8*)&p_s[(2 * w + 1) * 264 + (col & 7) * 32 + 8 * g];
            const bf16x8 B0 = *(const bf16x8*)&eeT_s[(2 * w + 0) * 640 + col * 40 + 8 * g];
            const bf16x8 B1 = *(const bf16x8*)&eeT_s[(2 * w + 1) * 640 + col * 40 + 8 * g];
            const float4 av0 = *(const float4*)&a_s[(2 * w + 0) * 8 + ((4 * g) & 7)];
            const float4 av1 = *(const float4*)&a_s[(2 * w + 1) * 8 + ((4 * g) & 7)];
            acce0[0] *= av0.x; acce0[1] *= av0.y; acce0[2] *= av0.z; acce0[3] *= av0.w;
            acce1[0] *= av1.x; acce1[1] *= av1.y; acce1[2] *= av1.z; acce1[3] *= av1.w;
            acce0 = __builtin_amdgcn_mfma_f32_16x16x32_bf16(Pn0, B0, acce0, 0, 0, 0);
            acce1 = __builtin_amdgcn_mfma_f32_16x16x32_bf16(Pn1, B1, acce1, 0, 0, 0);
        }

        // staging write of next chunk into the other natural buffer
        if (it < 15) {
            u16* dst = (u16*)ee_s[(it + 1) & 1];
            *(uint4*)&dst[sn * 520 + sm * 16] =
                make_uint4(cvt2(r0.x, r0.y), cvt2(r0.z, r0.w), cvt2(r1.x, r1.y), cvt2(r1.z, r1.w));
            *(uint4*)&dst[sn * 520 + sm * 16 + 8] =
                make_uint4(cvt2(r2.x, r2.y), cvt2(r2.z, r2.w), cvt2(r3.x, r3.y), cvt2(r3.z, r3.w));
        }
        __syncthreads();
    }

    // epilogue
    Ls += __shfl_xor(Ls, 16);
    Ls += __shfl_xor(Ls, 32);

    {
        float* avp = accv_ws + (((size_t)ck * 8 + h) * NN + n0 + col) * 32;
#pragma unroll
        for (int reg = 0; reg < 4; ++reg) {
            avp[4 * g + reg] = accpv0[reg];
            avp[16 + 4 * g + reg] = accpv1[reg];
        }
    }
    if (l < 32) {
#pragma unroll
        for (int s2 = 0; s2 < 2; ++s2) {
            const f32x4 acc = (s2 == 0) ? acce0 : acce1;
#pragma unroll
            for (int reg = 0; reg < 4; ++reg) {
                const int hr = 4 * g + reg;
                acce_ws[(((size_t)ck * 8 + hr) * NN + n0 + 2 * w + s2) * 16 + col] = acc[reg];
            }
        }
    }
    if (l < 16) {
        float* mlp = ml_ws + (((size_t)ck * 8 + h) * NN + n0 + col) * 2;
        mlp[0] = M;
        mlp[1] = Ls;
    }
}

// ---------- K3: combine 4 m-chunks + edge-value projection + output GEMM ----------
__global__ __launch_bounds__(256) void k3_combine(
    const float* __restrict__ accv_ws, const float* __restrict__ acce_ws,
    const float* __restrict__ ml_ws, const float* __restrict__ ev_g,
    const float* __restrict__ ot_g, float* __restrict__ out_g) {
    __shared__ float w_s[64][4];
    __shared__ float ae_s[8 * 8 * 16];
    __shared__ __align__(16) float av_s[256 * 8];  // [k=h*32+v][n_l]
    const int t = threadIdx.x;
    const int n0 = blockIdx.x * 8;
    if (t < 64) {
        const int h = t >> 3, nl = t & 7, gn = n0 + nl;
        float Mc[4], Lc[4];
#pragma unroll
        for (int c = 0; c < 4; ++c) {
            Mc[c] = ml_ws[(((size_t)c * 8 + h) * NN + gn) * 2 + 0];
            Lc[c] = ml_ws[(((size_t)c * 8 + h) * NN + gn) * 2 + 1];
        }
        float Mx = fmaxf(fmaxf(Mc[0], Mc[1]), fmaxf(Mc[2], Mc[3]));
        float ex[4], den = 0.f;
#pragma unroll
        for (int c = 0; c < 4; ++c) { ex[c] = __expf(Mc[c] - Mx); den += ex[c] * Lc[c]; }
        const float inv = 1.0f / den;
#pragma unroll
        for (int c = 0; c < 4; ++c) w_s[t][c] = ex[c] * inv;
    }
    __syncthreads();
#pragma unroll
    for (int c2 = 0; c2 < 4; ++c2) {
        const int idx = t + c2 * 256;  // 1024 = 8n*8h*16e
        const int nl = idx >> 7, h = (idx >> 4) & 7, e = idx & 15;
        const int gn = n0 + nl;
        float s = 0.f;
#pragma unroll
        for (int c = 0; c < 4; ++c)
            s += w_s[h * 8 + nl][c] * acce_ws[(((size_t)c * 8 + h) * NN + gn) * 16 + e];
        ae_s[(nl * 8 + h) * 16 + e] = s;
    }
    __syncthreads();
#pragma unroll
    for (int c2 = 0; c2 < 8; ++c2) {
        const int idx = t + c2 * 256;  // 2048 = 8n*8h*32v
        const int nl = idx >> 8, h = (idx >> 5) & 7, v = idx & 31;
        const int gn = n0 + nl;
        float x = 0.f;
#pragma unroll
        for (int c = 0; c < 4; ++c)
            x += w_s[h * 8 + nl][c] * accv_ws[(((size_t)c * 8 + h) * NN + gn) * 32 + v];
        const float* aep = &ae_s[(nl * 8 + h) * 16];
#pragma unroll
        for (int e = 0; e < 16; ++e) x = fmaf(aep[e], ev_g[e * 32 + v], x);
        av_s[(h * 32 + v) * 8 + nl] = x;
    }
    __syncthreads();
    {
        const int o = t;
        float r0 = 0, r1 = 0, r2 = 0, r3 = 0, r4 = 0, r5 = 0, r6 = 0, r7 = 0;
#pragma unroll 4
        for (int k = 0; k < 256; ++k) {
            const float w = ot_g[k * 256 + o];
            const float* av = &av_s[k * 8];
            r0 = fmaf(av[0], w, r0); r1 = fmaf(av[1], w, r1);
            r2 = fmaf(av[2], w, r2); r3 = fmaf(av[3], w, r3);
            r4 = fmaf(av[4], w, r4); r5 = fmaf(av[5], w, r5);
            r6 = fmaf(av[6], w, r6); r7 = fmaf(av[7], w, r7);
        }
        out_g[(size_t)(n0 + 0) * 256 + o] = r0;
        out_g[(size_t)(n0 + 1) * 256 + o] = r1;
        out_g[(size_t)(n0 + 2) * 256 + o] = r2;
        out_g[(size_t)(n0 + 3) * 256 + o] = r3;
        out_g[(size_t)(n0 + 4) * 256 + o] = r4;
        out_g[(size_t)(n0 + 5) * 256 + o] = r5;
        out_g[(size_t)(n0 + 6) * 256 + o] = r6;
        out_g[(size_t)(n0 + 7) * 256 + o] = r7;
    }
}

extern "C" void kernel_launch(void* const* d_in, const int* in_sizes, int n_in,
                              void* d_out, int out_size, void* d_ws, size_t ws_size,
                              hipStream_t stream) {
    (void)in_sizes; (void)n_in; (void)out_size; (void)ws_size;
    const float* ee = (const float*)d_in[0];
    const float* node = (const float*)d_in[1];
    const float* qt = (const float*)d_in[2];
    const float* nkt = (const float*)d_in[3];
    const float* ek = (const float*)d_in[4];
    const float* nvt = (const float*)d_in[5];
    const float* ev = (const float*)d_in[6];
    const float* ot = (const float*)d_in[7];
    float* out = (float*)d_out;

    char* ws = (char*)d_ws;
    u16* qbf = (u16*)(ws);                             // 1 MB  [8][2048][32] bf16
    u16* qebf = (u16*)(ws + (1u << 20));               // 0.5 MB [8][2048][16] bf16
    u16* nk_ws = (u16*)(ws + (1u << 20) + (1u << 19)); // 1 MB  [8][2048][32] bf16
    u16* nvT_ws = (u16*)(ws + (2u << 20) + (1u << 19));// 1 MB [8][32][2048] bf16
    float* accv_ws = (float*)(ws + (3u << 20) + (1u << 19)); // 8 MB [4][8][2048][32]
    float* acce_ws = (float*)(ws + (11u << 20) + (1u << 19));// 4 MB [4][8][2048][16]
    float* ml_ws = (float*)(ws + (15u << 20) + (1u << 19));  // 0.5 MB [4][8][2048][2]

    hipLaunchKernelGGL(k1_precompute, dim3(512), dim3(256), 0, stream,
                       node, qt, nkt, nvt, ek, qbf, qebf, nk_ws, nvT_ws);
    hipLaunchKernelGGL(k2_attn, dim3(512), dim3(512), 0, stream,
                       ee, qbf, qebf, nk_ws, nvT_ws, accv_ws, acce_ws, ml_ws);
    hipLaunchKernelGGL(k3_combine, dim3(256), dim3(256), 0, stream,
                       accv_ws, acce_ws, ml_ws, ev, ot, out);
}

// Round 6
// 149.125 us; speedup vs baseline: 12.8721x; 1.0194x over previous
//
#include <hip/hip_runtime.h>
#include <hip/hip_bf16.h>

typedef unsigned short u16;
typedef unsigned int u32;
typedef __attribute__((ext_vector_type(8))) short bf16x8;
typedef __attribute__((ext_vector_type(4))) float f32x4;

#define NN 2048
#define DM 256
#define ED 16
#define HH 8
#define QK 32
#define VV 32
#define OUTD 256

// ---------- helpers ----------
__device__ __forceinline__ u16 f2bf(float f) {
    __hip_bfloat16 h = __float2bfloat16(f);
    return *reinterpret_cast<u16*>(&h);
}
__device__ __forceinline__ u32 cvt2(float a, float b) {
    __hip_bfloat162 h = __float22bfloat162_rn(make_float2(a, b));
    return *reinterpret_cast<u32*>(&h);
}

// ---------- K1: projections ----------
// grid 512 = 8 h * 64 n-tiles(32 rows), 256 thr
// qbf bf16 [h][n][32] (scaled 1/sqrt(32)); qebf bf16 [h][n][16] (scaled);
// nk bf16 [h][m][32]; nvT bf16 [h][v=32][n=2048] (plain transpose)
__global__ __launch_bounds__(256) void k1_precompute(
    const float* __restrict__ node_g, const float* __restrict__ qt_g,
    const float* __restrict__ nkt_g, const float* __restrict__ nvt_g,
    const float* __restrict__ ek_g,
    u16* __restrict__ qbf, u16* __restrict__ qebf,
    u16* __restrict__ nk_ws, u16* __restrict__ nvT_ws) {
    __shared__ __align__(16) float node_s[32][256];
    __shared__ __align__(16) float qtmp_s[32][32];
    const int t = threadIdx.x;
    const int h = blockIdx.x >> 6;
    const int n0 = (blockIdx.x & 63) * 32;
#pragma unroll
    for (int c = 0; c < 8; ++c) {
        const int ci = t + c * 256;
        const int nl = ci >> 6, d4 = ci & 63;
        *(float4*)&node_s[nl][d4 * 4] =
            *(const float4*)&node_g[(size_t)(n0 + nl) * 256 + d4 * 4];
    }
    __syncthreads();
    const int q = t & 31, nb = t >> 5;
    const float scale = 0.17677669529663689f;  // 1/sqrt(32)

#define PROJ_LOOP(Wp, STORE0, STORE1, STORE2, STORE3)                          \
    {                                                                          \
        const float* W = Wp;                                                   \
        float a0 = 0.f, a1 = 0.f, a2 = 0.f, a3 = 0.f;                          \
        for (int d4 = 0; d4 < 64; ++d4) {                                      \
            const float w0 = W[(d4 * 4 + 0) * 32 + q];                         \
            const float w1 = W[(d4 * 4 + 1) * 32 + q];                         \
            const float w2 = W[(d4 * 4 + 2) * 32 + q];                         \
            const float w3 = W[(d4 * 4 + 3) * 32 + q];                         \
            float4 nd;                                                         \
            nd = *(const float4*)&node_s[nb][d4 * 4];                          \
            a0 += nd.x * w0 + nd.y * w1 + nd.z * w2 + nd.w * w3;               \
            nd = *(const float4*)&node_s[nb + 8][d4 * 4];                      \
            a1 += nd.x * w0 + nd.y * w1 + nd.z * w2 + nd.w * w3;               \
            nd = *(const float4*)&node_s[nb + 16][d4 * 4];                     \
            a2 += nd.x * w0 + nd.y * w1 + nd.z * w2 + nd.w * w3;               \
            nd = *(const float4*)&node_s[nb + 24][d4 * 4];                     \
            a3 += nd.x * w0 + nd.y * w1 + nd.z * w2 + nd.w * w3;               \
        }                                                                      \
        STORE0; STORE1; STORE2; STORE3;                                        \
    }

    // query (scaled) -> qtmp_s (f32) + qbf (bf16)
    PROJ_LOOP(qt_g + h * (DM * QK),
        { float v = a0 * scale; qtmp_s[nb][q] = v;      qbf[((size_t)h * NN + n0 + nb) * 32 + q] = f2bf(v); },
        { float v = a1 * scale; qtmp_s[nb + 8][q] = v;  qbf[((size_t)h * NN + n0 + nb + 8) * 32 + q] = f2bf(v); },
        { float v = a2 * scale; qtmp_s[nb + 16][q] = v; qbf[((size_t)h * NN + n0 + nb + 16) * 32 + q] = f2bf(v); },
        { float v = a3 * scale; qtmp_s[nb + 24][q] = v; qbf[((size_t)h * NN + n0 + nb + 24) * 32 + q] = f2bf(v); })
    // node_key -> bf16 [h][m][q]
    PROJ_LOOP(nkt_g + h * (DM * QK),
        { nk_ws[((size_t)h * NN + n0 + nb) * 32 + q] = f2bf(a0); },
        { nk_ws[((size_t)h * NN + n0 + nb + 8) * 32 + q] = f2bf(a1); },
        { nk_ws[((size_t)h * NN + n0 + nb + 16) * 32 + q] = f2bf(a2); },
        { nk_ws[((size_t)h * NN + n0 + nb + 24) * 32 + q] = f2bf(a3); })
    // node_value -> bf16 transposed [h][v][n]
    PROJ_LOOP(nvt_g + h * (DM * QK),
        { nvT_ws[((size_t)h * 32 + q) * NN + n0 + nb] = f2bf(a0); },
        { nvT_ws[((size_t)h * 32 + q) * NN + n0 + nb + 8] = f2bf(a1); },
        { nvT_ws[((size_t)h * 32 + q) * NN + n0 + nb + 16] = f2bf(a2); },
        { nvT_ws[((size_t)h * 32 + q) * NN + n0 + nb + 24] = f2bf(a3); })
#undef PROJ_LOOP
    __syncthreads();
    // qe[h,n,e] = sum_q qtmp[n][q] * ek[e][q]   (scaled) -> bf16
#pragma unroll
    for (int c = 0; c < 2; ++c) {
        const int idx = t + c * 256;
        const int nl = idx >> 4, e = idx & 15;
        float s = 0.f;
#pragma unroll
        for (int qq = 0; qq < 32; ++qq) s = fmaf(qtmp_s[nl][qq], ek_g[e * 32 + qq], s);
        qebf[((size_t)h * NN + n0 + nl) * 16 + e] = f2bf(s);
    }
}

// ---------- K2: fused MFMA attention ----------
// grid 512 = 128 n-tiles(16 rows) * 4 m-chunks(512 m each), 512 thr = 8 waves = 8 heads
// __launch_bounds__(512,4): 4 waves/EU -> 2 blocks/CU (VGPR<=128); LDS 79.4KB*2 <= 160KB
__global__ __launch_bounds__(512, 4) void k2_attn(
    const float* __restrict__ ee_g, const u16* __restrict__ qbf,
    const u16* __restrict__ qebf, const u16* __restrict__ nk_g,
    const u16* __restrict__ nvT_g, float* __restrict__ accv_ws,
    float* __restrict__ acce_ws, float* __restrict__ ml_ws) {
    // ee (natural, e-contig) double-buffered bf16 [16n][32m][16e] (n-stride 520 u16)
    __shared__ __align__(16) u16 ee_s[2][16 * 520];
    // ee transposed (m-contig) single-buffered bf16 [16n][16e][32m+8pad] (e-stride 40, n-stride 640)
    __shared__ __align__(16) u16 eeT_s[16 * 640];
    // edge logits f32 [16n][8h][32m] (n-stride 260)
    __shared__ __align__(16) float el_s[16 * 260];
    // P bf16 [16n][8h][32m] plain order (n-stride 264)
    __shared__ __align__(16) u16 p_s[16 * 264];
    // rescale factors f32 [16n][8h]
    __shared__ float a_s[16 * 8];

    const int t = threadIdx.x;
    const int w = t >> 6;          // wave = head
    const int l = t & 63;
    const int col = l & 15;
    const int g = l >> 4;          // 0..3
    const int h = w;
    const int nt = blockIdx.x >> 2;
    const int ck = blockIdx.x & 3;
    const int n0 = nt * 16;
    const int mbase = ck * 512;
    // staging role: n-row sn, m-pair sj (m = 2sj, 2sj+1), e-half seh (e = 8seh..8seh+7)
    const int sn = t >> 5, sj = (t >> 1) & 15, seh = t & 1;

    // persistent fragments
    const bf16x8 Qfrag = *(const bf16x8*)&qbf[((size_t)h * NN + n0 + col) * 32 + 8 * g];
    bf16x8 qeA[2];
#pragma unroll
    for (int s2 = 0; s2 < 2; ++s2) {
        bf16x8 z = {0, 0, 0, 0, 0, 0, 0, 0};
        if (col < 8 && g < 2)
            z = *(const bf16x8*)&qebf[((size_t)col * NN + n0 + 2 * w + s2) * 16 + 8 * g];
        qeA[s2] = z;
    }

    f32x4 accpv0 = {0.f, 0.f, 0.f, 0.f}, accpv1 = {0.f, 0.f, 0.f, 0.f};
    f32x4 acce0 = {0.f, 0.f, 0.f, 0.f}, acce1 = {0.f, 0.f, 0.f, 0.f};
    float M = -INFINITY, Ls = 0.f;

    // stage chunk 0 into ee_s[0]; regs keep chunk 0 for the iter-0 eeT write
    // r0/r1 = (m=2sj, e=8seh..), r2/r3 = (m=2sj+1, e=8seh..)
    float4 r0, r1, r2, r3;
    {
        const float* src = ee_g + ((size_t)(n0 + sn) * NN + mbase + 2 * sj) * 16 + seh * 8;
        r0 = *(const float4*)(src);
        r1 = *(const float4*)(src + 4);
        r2 = *(const float4*)(src + 16);
        r3 = *(const float4*)(src + 20);
        *(uint4*)&ee_s[0][sn * 520 + (2 * sj) * 16 + seh * 8] =
            make_uint4(cvt2(r0.x, r0.y), cvt2(r0.z, r0.w), cvt2(r1.x, r1.y), cvt2(r1.z, r1.w));
        *(uint4*)&ee_s[0][sn * 520 + (2 * sj + 1) * 16 + seh * 8] =
            make_uint4(cvt2(r2.x, r2.y), cvt2(r2.z, r2.w), cvt2(r3.x, r3.y), cvt2(r3.z, r3.w));
    }
    __syncthreads();

    const f32x4 zf = {0.f, 0.f, 0.f, 0.f};

#pragma unroll 1
    for (int it = 0; it < 16; ++it) {
        const int m0 = mbase + it * 32;
        const u16* eeb = ee_s[it & 1];

        // write eeT for CURRENT chunk from regs: 8x ds_write_b32 (m-pairs packed)
        {
            u32* dstT = (u32*)&eeT_s[sn * 640 + (seh * 8) * 40 + 2 * sj];
            dstT[0 * 20] = cvt2(r0.x, r2.x);
            dstT[1 * 20] = cvt2(r0.y, r2.y);
            dstT[2 * 20] = cvt2(r0.z, r2.z);
            dstT[3 * 20] = cvt2(r0.w, r2.w);
            dstT[4 * 20] = cvt2(r1.x, r3.x);
            dstT[5 * 20] = cvt2(r1.y, r3.y);
            dstT[6 * 20] = cvt2(r1.z, r3.z);
            dstT[7 * 20] = cvt2(r1.w, r3.w);
        }

        // prefetch next chunk into regs
        if (it < 15) {
            const float* src = ee_g + ((size_t)(n0 + sn) * NN + m0 + 32 + 2 * sj) * 16 + seh * 8;
            r0 = *(const float4*)(src);
            r1 = *(const float4*)(src + 4);
            r2 = *(const float4*)(src + 16);
            r3 = *(const float4*)(src + 20);
        }

        // step a: node logits S^T = K · Q^T  (two 16-m subtiles)
        f32x4 sn0, sn1;
        {
            const bf16x8 Kf0 = *(const bf16x8*)&nk_g[((size_t)h * NN + m0 + col) * 32 + 8 * g];
            const bf16x8 Kf1 = *(const bf16x8*)&nk_g[((size_t)h * NN + m0 + 16 + col) * 32 + 8 * g];
            sn0 = __builtin_amdgcn_mfma_f32_16x16x32_bf16(Kf0, Qfrag, zf, 0, 0, 0);
            sn1 = __builtin_amdgcn_mfma_f32_16x16x32_bf16(Kf1, Qfrag, zf, 0, 0, 0);
        }

        // step b: edge logits per n-slot: D[h][m] = qe_n · ee_n^T
#pragma unroll
        for (int s2 = 0; s2 < 2; ++s2) {
            const int nsl = 2 * w + s2;
#pragma unroll
            for (int s = 0; s < 2; ++s) {
                bf16x8 Bf = {0, 0, 0, 0, 0, 0, 0, 0};
                if (g < 2)
                    Bf = *(const bf16x8*)&eeb[nsl * 520 + (s * 16 + col) * 16 + 8 * g];
                f32x4 d = __builtin_amdgcn_mfma_f32_16x16x32_bf16(qeA[s2], Bf, zf, 0, 0, 0);
                if (l < 32) {  // rows h = 4g+reg < 8
#pragma unroll
                    for (int reg = 0; reg < 4; ++reg)
                        el_s[nsl * 260 + (4 * g + reg) * 32 + s * 16 + col] = d[reg];
                }
            }
        }
        __syncthreads();

        // step d: combine logits + online softmax (thread owns n=col, m rows 4g+r / 16+4g+r)
        {
            const float4 e0 = *(const float4*)&el_s[col * 260 + h * 32 + 4 * g];
            const float4 e1 = *(const float4*)&el_s[col * 260 + h * 32 + 16 + 4 * g];
            float lv[8];
            lv[0] = sn0[0] + e0.x; lv[1] = sn0[1] + e0.y;
            lv[2] = sn0[2] + e0.z; lv[3] = sn0[3] + e0.w;
            lv[4] = sn1[0] + e1.x; lv[5] = sn1[1] + e1.y;
            lv[6] = sn1[2] + e1.z; lv[7] = sn1[3] + e1.w;
            float tm = fmaxf(fmaxf(fmaxf(lv[0], lv[1]), fmaxf(lv[2], lv[3])),
                             fmaxf(fmaxf(lv[4], lv[5]), fmaxf(lv[6], lv[7])));
            tm = fmaxf(tm, __shfl_xor(tm, 16));
            tm = fmaxf(tm, __shfl_xor(tm, 32));
            const float nM = fmaxf(M, tm);
            const float a = __expf(M - nM);
            M = nM;
            Ls *= a;
#pragma unroll
            for (int r = 0; r < 4; ++r) { accpv0[r] *= a; accpv1[r] *= a; }
            float p[8];
#pragma unroll
            for (int i = 0; i < 8; ++i) { p[i] = __expf(lv[i] - nM); Ls += p[i]; }
            // write P in plain m-order: m=4g+i and m=16+4g+i
            uint2 pk0, pk1;
            pk0.x = cvt2(p[0], p[1]); pk0.y = cvt2(p[2], p[3]);
            pk1.x = cvt2(p[4], p[5]); pk1.y = cvt2(p[6], p[7]);
            *(uint2*)&p_s[col * 264 + h * 32 + 4 * g] = pk0;
            *(uint2*)&p_s[col * 264 + h * 32 + 16 + 4 * g] = pk1;
            if (l < 16) a_s[col * 8 + h] = a;
        }
        __syncthreads();

        // step g: PV: D[v][n] += V^T · P^T   (own head; plain m-order both sides)
        {
            const bf16x8 Pf = *(const bf16x8*)&p_s[col * 264 + h * 32 + 8 * g];
            const bf16x8 Vf0 = *(const bf16x8*)&nvT_g[((size_t)h * 32 + col) * NN + m0 + 8 * g];
            const bf16x8 Vf1 = *(const bf16x8*)&nvT_g[((size_t)h * 32 + 16 + col) * NN + m0 + 8 * g];
            accpv0 = __builtin_amdgcn_mfma_f32_16x16x32_bf16(Vf0, Pf, accpv0, 0, 0, 0);
            accpv1 = __builtin_amdgcn_mfma_f32_16x16x32_bf16(Vf1, Pf, accpv1, 0, 0, 0);
        }

        // step h: acce per n-slot: D[h][e] = a∘D + P_n · ee_n
        // B from eeT (m-contig): B[k=8g+j][col=e] = eeT[nsl][col][8g+j] == ee[nsl][8g+j][col]
        {
            const bf16x8 Pn0 = *(const bf16x8*)&p_s[(2 * w + 0) * 264 + (col & 7) * 32 + 8 * g];
            const bf16x8 Pn1 = *(const bf16x8*)&p_s[(2 * w + 1) * 264 + (col & 7) * 32 + 8 * g];
            const bf16x8 B0 = *(const bf16x8*)&eeT_s[(2 * w + 0) * 640 + col * 40 + 8 * g];
            const bf16x8 B1 = *(const bf16x8*)&eeT_s[(2 * w + 1) * 640 + col * 40 + 8 * g];
            const float4 av0 = *(const float4*)&a_s[(2 * w + 0) * 8 + ((4 * g) & 7)];
            const float4 av1 = *(const float4*)&a_s[(2 * w + 1) * 8 + ((4 * g) & 7)];
            acce0[0] *= av0.x; acce0[1] *= av0.y; acce0[2] *= av0.z; acce0[3] *= av0.w;
            acce1[0] *= av1.x; acce1[1] *= av1.y; acce1[2] *= av1.z; acce1[3] *= av1.w;
            acce0 = __builtin_amdgcn_mfma_f32_16x16x32_bf16(Pn0, B0, acce0, 0, 0, 0);
            acce1 = __builtin_amdgcn_mfma_f32_16x16x32_bf16(Pn1, B1, acce1, 0, 0, 0);
        }

        // staging write of next chunk into the other natural buffer
        if (it < 15) {
            u16* dst = (u16*)ee_s[(it + 1) & 1];
            *(uint4*)&dst[sn * 520 + (2 * sj) * 16 + seh * 8] =
                make_uint4(cvt2(r0.x, r0.y), cvt2(r0.z, r0.w), cvt2(r1.x, r1.y), cvt2(r1.z, r1.w));
            *(uint4*)&dst[sn * 520 + (2 * sj + 1) * 16 + seh * 8] =
                make_uint4(cvt2(r2.x, r2.y), cvt2(r2.z, r2.w), cvt2(r3.x, r3.y), cvt2(r3.z, r3.w));
        }
        __syncthreads();
    }

    // epilogue
    Ls += __shfl_xor(Ls, 16);
    Ls += __shfl_xor(Ls, 32);

    {
        float* avp = accv_ws + (((size_t)ck * 8 + h) * NN + n0 + col) * 32;
#pragma unroll
        for (int reg = 0; reg < 4; ++reg) {
            avp[4 * g + reg] = accpv0[reg];
            avp[16 + 4 * g + reg] = accpv1[reg];
        }
    }
    if (l < 32) {
#pragma unroll
        for (int s2 = 0; s2 < 2; ++s2) {
            const f32x4 acc = (s2 == 0) ? acce0 : acce1;
#pragma unroll
            for (int reg = 0; reg < 4; ++reg) {
                const int hr = 4 * g + reg;
                acce_ws[(((size_t)ck * 8 + hr) * NN + n0 + 2 * w + s2) * 16 + col] = acc[reg];
            }
        }
    }
    if (l < 16) {
        float* mlp = ml_ws + (((size_t)ck * 8 + h) * NN + n0 + col) * 2;
        mlp[0] = M;
        mlp[1] = Ls;
    }
}

// ---------- K3: combine 4 m-chunks + edge-value projection + output GEMM ----------
__global__ __launch_bounds__(256) void k3_combine(
    const float* __restrict__ accv_ws, const float* __restrict__ acce_ws,
    const float* __restrict__ ml_ws, const float* __restrict__ ev_g,
    const float* __restrict__ ot_g, float* __restrict__ out_g) {
    __shared__ float w_s[64][4];
    __shared__ float ae_s[8 * 8 * 16];
    __shared__ __align__(16) float av_s[256 * 8];  // [k=h*32+v][n_l]
    const int t = threadIdx.x;
    const int n0 = blockIdx.x * 8;
    if (t < 64) {
        const int h = t >> 3, nl = t & 7, gn = n0 + nl;
        float Mc[4], Lc[4];
#pragma unroll
        for (int c = 0; c < 4; ++c) {
            Mc[c] = ml_ws[(((size_t)c * 8 + h) * NN + gn) * 2 + 0];
            Lc[c] = ml_ws[(((size_t)c * 8 + h) * NN + gn) * 2 + 1];
        }
        float Mx = fmaxf(fmaxf(Mc[0], Mc[1]), fmaxf(Mc[2], Mc[3]));
        float ex[4], den = 0.f;
#pragma unroll
        for (int c = 0; c < 4; ++c) { ex[c] = __expf(Mc[c] - Mx); den += ex[c] * Lc[c]; }
        const float inv = 1.0f / den;
#pragma unroll
        for (int c = 0; c < 4; ++c) w_s[t][c] = ex[c] * inv;
    }
    __syncthreads();
#pragma unroll
    for (int c2 = 0; c2 < 4; ++c2) {
        const int idx = t + c2 * 256;  // 1024 = 8n*8h*16e
        const int nl = idx >> 7, h = (idx >> 4) & 7, e = idx & 15;
        const int gn = n0 + nl;
        float s = 0.f;
#pragma unroll
        for (int c = 0; c < 4; ++c)
            s += w_s[h * 8 + nl][c] * acce_ws[(((size_t)c * 8 + h) * NN + gn) * 16 + e];
        ae_s[(nl * 8 + h) * 16 + e] = s;
    }
    __syncthreads();
#pragma unroll
    for (int c2 = 0; c2 < 8; ++c2) {
        const int idx = t + c2 * 256;  // 2048 = 8n*8h*32v
        const int nl = idx >> 8, h = (idx >> 5) & 7, v = idx & 31;
        const int gn = n0 + nl;
        float x = 0.f;
#pragma unroll
        for (int c = 0; c < 4; ++c)
            x += w_s[h * 8 + nl][c] * accv_ws[(((size_t)c * 8 + h) * NN + gn) * 32 + v];
        const float* aep = &ae_s[(nl * 8 + h) * 16];
#pragma unroll
        for (int e = 0; e < 16; ++e) x = fmaf(aep[e], ev_g[e * 32 + v], x);
        av_s[(h * 32 + v) * 8 + nl] = x;
    }
    __syncthreads();
    {
        const int o = t;
        float r0 = 0, r1 = 0, r2 = 0, r3 = 0, r4 = 0, r5 = 0, r6 = 0, r7 = 0;
#pragma unroll 4
        for (int k = 0; k < 256; ++k) {
            const float w = ot_g[k * 256 + o];
            const float* av = &av_s[k * 8];
            r0 = fmaf(av[0], w, r0); r1 = fmaf(av[1], w, r1);
            r2 = fmaf(av[2], w, r2); r3 = fmaf(av[3], w, r3);
            r4 = fmaf(av[4], w, r4); r5 = fmaf(av[5], w, r5);
            r6 = fmaf(av[6], w, r6); r7 = fmaf(av[7], w, r7);
        }
        out_g[(size_t)(n0 + 0) * 256 + o] = r0;
        out_g[(size_t)(n0 + 1) * 256 + o] = r1;
        out_g[(size_t)(n0 + 2) * 256 + o] = r2;
        out_g[(size_t)(n0 + 3) * 256 + o] = r3;
        out_g[(size_t)(n0 + 4) * 256 + o] = r4;
        out_g[(size_t)(n0 + 5) * 256 + o] = r5;
        out_g[(size_t)(n0 + 6) * 256 + o] = r6;
        out_g[(size_t)(n0 + 7) * 256 + o] = r7;
    }
}

extern "C" void kernel_launch(void* const* d_in, const int* in_sizes, int n_in,
                              void* d_out, int out_size, void* d_ws, size_t ws_size,
                              hipStream_t stream) {
    (void)in_sizes; (void)n_in; (void)out_size; (void)ws_size;
    const float* ee = (const float*)d_in[0];
    const float* node = (const float*)d_in[1];
    const float* qt = (const float*)d_in[2];
    const float* nkt = (const float*)d_in[3];
    const float* ek = (const float*)d_in[4];
    const float* nvt = (const float*)d_in[5];
    const float* ev = (const float*)d_in[6];
    const float* ot = (const float*)d_in[7];
    float* out = (float*)d_out;

    char* ws = (char*)d_ws;
    u16* qbf = (u16*)(ws);                             // 1 MB  [8][2048][32] bf16
    u16* qebf = (u16*)(ws + (1u << 20));               // 0.5 MB [8][2048][16] bf16
    u16* nk_ws = (u16*)(ws + (1u << 20) + (1u << 19)); // 1 MB  [8][2048][32] bf16
    u16* nvT_ws = (u16*)(ws + (2u << 20) + (1u << 19));// 1 MB [8][32][2048] bf16
    float* accv_ws = (float*)(ws + (3u << 20) + (1u << 19)); // 8 MB [4][8][2048][32]
    float* acce_ws = (float*)(ws + (11u << 20) + (1u << 19));// 4 MB [4][8][2048][16]
    float* ml_ws = (float*)(ws + (15u << 20) + (1u << 19));  // 0.5 MB [4][8][2048][2]

    hipLaunchKernelGGL(k1_precompute, dim3(512), dim3(256), 0, stream,
                       node, qt, nkt, nvt, ek, qbf, qebf, nk_ws, nvT_ws);
    hipLaunchKernelGGL(k2_attn, dim3(512), dim3(512), 0, stream,
                       ee, qbf, qebf, nk_ws, nvT_ws, accv_ws, acce_ws, ml_ws);
    hipLaunchKernelGGL(k3_combine, dim3(256), dim3(256), 0, stream,
                       accv_ws, acce_ws, ml_ws, ev, ot, out);
}